// Round 17
// baseline (363.938 us; speedup 1.0000x reference)
//
#include <hip/hip_runtime.h>

#define N_DIM 8192
#define E_DIM 4096
#define BK    128
#define NT    (E_DIM / BK)   // 32 K-tiles

using int4v  = __attribute__((ext_vector_type(4))) int;
using i32x16 = __attribute__((ext_vector_type(16))) int;

__device__ __forceinline__ void async16(const void* g, void* l) {
  __builtin_amdgcn_global_load_lds(
      (const __attribute__((address_space(1))) unsigned int*)g,
      (__attribute__((address_space(3))) unsigned int*)l, 16, 0, 0);
}

// ---- kernel 1: fused degree + per-row quantize of A + rowsum + wmax ----
__global__ __launch_bounds__(256) void k_prepA(const float* __restrict__ H,
                                               const float* __restrict__ W,
                                               float* __restrict__ d,
                                               float* __restrict__ sA,
                                               int* __restrict__ rsA,
                                               float* __restrict__ wmax,
                                               signed char* __restrict__ A) {
  const int row  = blockIdx.x * 4 + (threadIdx.x >> 6);
  const int lane = threadIdx.x & 63;
  const float* hrow = H + (size_t)row * E_DIM;
  float4 h[16];
  float s = 0.f, m = 0.f, wm = 0.f;
#pragma unroll
  for (int i = 0; i < 16; ++i) {
    h[i] = *reinterpret_cast<const float4*>(hrow + lane * 4 + i * 256);
    float4 w = *reinterpret_cast<const float4*>(W + lane * 4 + i * 256);
    s += h[i].x * w.x + h[i].y * w.y + h[i].z * w.z + h[i].w * w.w;
    m = fmaxf(m, fmaxf(fmaxf(h[i].x, h[i].y), fmaxf(h[i].z, h[i].w)));
    wm = fmaxf(wm, fmaxf(fmaxf(w.x, w.y), fmaxf(w.z, w.w)));
  }
#pragma unroll
  for (int off = 1; off < 64; off <<= 1) {
    s += __shfl_xor(s, off);
    m = fmaxf(m, __shfl_xor(m, off));
    wm = fmaxf(wm, __shfl_xor(wm, off));
  }
  const float q = 127.0f / m;
  signed char* arow = A + (size_t)row * E_DIM;
  int rs = 0;
#pragma unroll
  for (int i = 0; i < 16; ++i) {
    const int b0 = __float2int_rn(h[i].x * q);
    const int b1 = __float2int_rn(h[i].y * q);
    const int b2 = __float2int_rn(h[i].z * q);
    const int b3 = __float2int_rn(h[i].w * q);
    rs += b0 + b1 + b2 + b3;
    const unsigned int pk = (unsigned)b0 | ((unsigned)b1 << 8) |
                            ((unsigned)b2 << 16) | ((unsigned)b3 << 24);
    *reinterpret_cast<unsigned int*>(arow + lane * 4 + i * 256) = pk;
  }
#pragma unroll
  for (int off = 1; off < 64; off <<= 1) rs += __shfl_xor(rs, off);
  if (lane == 0) {
    const float dv = rsqrtf(s);
    d[row]   = dv;
    sA[row]  = dv * m * (1.0f / 127.0f);
    rsA[row] = rs;
    if (blockIdx.x == 0 && threadIdx.x == 0) wmax[0] = wm;
  }
}

// ---- kernel 2: Bt_i8[j][e] = round(W_e*R[e][j]*255/wmax) - 128 (d_j cancels) ----
__global__ __launch_bounds__(256) void k_makeB(const float* __restrict__ R,
                                               const float* __restrict__ W,
                                               const float* __restrict__ scal,
                                               signed char* __restrict__ Bt) {
  __shared__ float ft[128][132];
  __shared__ float wlds[128];
  const int j0 = blockIdx.x * 128;
  const int e0 = blockIdx.y * 128;
  const int t = threadIdx.x;
  const int c4 = (t & 31) * 4;
#pragma unroll
  for (int r = (t >> 5); r < 128; r += 8) {
    float4 v = *reinterpret_cast<const float4*>(&R[(size_t)(e0 + r) * N_DIM + j0 + c4]);
    *reinterpret_cast<float4*>(&ft[r][c4]) = v;
  }
  if (t < 128) wlds[t] = W[e0 + t] * (255.0f / scal[0]);
  __syncthreads();
  const int r = t >> 1, p = t & 1;
  union { signed char c[64]; int4v i4[4]; } o;
#pragma unroll
  for (int e = 0; e < 64; ++e) {
    const int ee = p * 64 + e;
    o.c[e] = (signed char)(__float2int_rn(ft[ee][r] * wlds[ee]) - 128);
  }
  signed char* dstp = Bt + (size_t)(j0 + r) * E_DIM + e0 + p * 64;
#pragma unroll
  for (int s2 = 0; s2 < 4; ++s2)
    *reinterpret_cast<int4v*>(dstp + s2 * 16) = o.i4[s2];
}

// ---- kernel 3: 256x256 i8 MFMA GEMM — R16 schedule, FRAGMENT-MAJOR LDS ----
// LDS physical layout = exact fragment read order, so every hot-loop
// ds_read_b128 is at (1KB-block + lane*16): lane-linear, conflict-free by
// construction. Staging decodes physical P -> (row,col) -> pre-computed global
// source (global_load_lds dest stays linear; source permutation = layout).
//   A region 16KB: addr(s,k,lane) = s*4096 + k*1024 + lane*16
//     row = s*32 + (lane&31), col = k*32 + (lane>>5)*16   [bijective]
//   B region 16KB: addr(s2,n,k,lane) = s2*8192 + n*4096 + k*1024 + lane*16
//     row = s2*64 + n*32 + (lane&31), col = k*32 + (lane>>5)*16  [bijective]
// Schedule/gates/phases byte-identical to R16 (no setprio).
__global__ __launch_bounds__(512, 2) void k_gemm(const signed char* __restrict__ A,
                                                 const signed char* __restrict__ B,
                                                 const float* __restrict__ scal,
                                                 const float* __restrict__ sA,
                                                 const int* __restrict__ rsA,
                                                 const float* __restrict__ d,
                                                 float* __restrict__ C) {
  __shared__ alignas(16) signed char lds[131072];  // A: 2x32KB, B: 2x32KB

  // bid -> xcd (hw round-robin bid%8) -> 16x8 rect; round rr = 4x8 sub-rect
  const int bid  = blockIdx.x;          // 1024 blocks
  const int xcd  = bid & 7;
  const int loc  = bid >> 3;            // 0..127 within XCD
  const int rr   = loc >> 5;            // round 0..3
  const int pos  = loc & 31;
  const int tm   = (xcd >> 2) * 16 + rr * 4 + (pos >> 3);  // 0..31
  const int tn   = (xcd & 3) * 8 + (pos & 7);              // 0..31
  const size_t rowBase = (size_t)tm * 256;
  const size_t colBase = (size_t)tn * 256;

  const int t = threadIdx.x, wid = t >> 6, lane = t & 63;
  const int l31 = lane & 31, hi32 = lane >> 5;

  // staging sources: decode physical LDS offset -> fragment-major (row,col)
  const signed char *pA0[2], *pA1[2], *pB0[2], *pB1[2];
#pragma unroll
  for (int j = 0; j < 2; ++j) {
    const int P  = j * 8192 + wid * 1024 + lane * 16;  // byte off in 16KB region
    const int lP = (P >> 4) & 63;                      // lane slot within 1KB
    const int kP = (P >> 10) & 3;                      // k-fragment
    const int colP = kP * 32 + (lP >> 5) * 16;         // byte col (i8 => elem col)
    // A: slice s = P>>12 (32 rows each)
    const int rowA = (P >> 12) * 32 + (lP & 31);
    pA0[j] = A + (rowBase +       rowA) * E_DIM + colP;
    pA1[j] = A + (rowBase + 128 + rowA) * E_DIM + colP;
    // B: slice s2 = P>>13 (64 rows), n = (P>>12)&1 (32 rows)
    const int rowB = (P >> 13) * 64 + ((P >> 12) & 1) * 32 + (lP & 31);
    pB0[j] = B + (colBase +       rowB) * E_DIM + colP;
    pB1[j] = B + (colBase + 128 + rowB) * E_DIM + colP;
  }
  const int dstw = wid * 1024;

#define STG(Pj, base_, kt)                                            \
  do {                                                                \
    async16(Pj[0] + (size_t)(kt) * BK, &lds[(base_) + dstw]);         \
    async16(Pj[1] + (size_t)(kt) * BK, &lds[(base_) + 8192 + dstw]);  \
  } while (0)

  // fragment read bases: lane-linear within each 1KB block
  const int aBase = (wid & 3) * 4096 + lane * 16;
  const int bBase = (wid >> 2) * 8192 + lane * 16;

  int4v af0[4], af1[4], bf[2][4];
  i32x16 acc[2][2][2] = {};  // [a-half][b-half][n]

#define RD_A(dst_, aH, cb)                                                        \
  do {                                                                            \
    _Pragma("unroll") for (int k = 0; k < 4; ++k)                                 \
      dst_[k] = *(const int4v*)&lds[(cb) * 32768 + (aH) * 16384 + aBase + k * 1024]; \
  } while (0)
#define RD_B(bH, cb)                                                              \
  do {                                                                            \
    _Pragma("unroll") for (int n = 0; n < 2; ++n)                                 \
      _Pragma("unroll") for (int k = 0; k < 4; ++k)                               \
        bf[n][k] = *(const int4v*)&lds[65536 + (cb) * 32768 + (bH) * 16384 +      \
                                       bBase + n * 4096 + k * 1024];              \
  } while (0)
#define MM(src_, a_, b_)                                                          \
  do {                                                                            \
    _Pragma("unroll") for (int n = 0; n < 2; ++n)                                 \
      _Pragma("unroll") for (int k = 0; k < 4; ++k)                               \
        acc[a_][b_][n] =                                                          \
            __builtin_amdgcn_mfma_i32_32x32x32_i8(src_[k], bf[n][k],              \
                                                  acc[a_][b_][n], 0, 0, 0);       \
  } while (0)
#define GATE(n_) asm volatile("s_waitcnt vmcnt(" #n_ ")" ::: "memory")

  // ---- prologue: stage tile 0 (A0,B0,A1,B1 -> buf0); gate(4) => A0,B0 landed ----
  STG(pA0, 0, 0);
  STG(pB0, 65536, 0);
  STG(pA1, 16384, 0);
  STG(pB1, 65536 + 16384, 0);
  GATE(4);
  __builtin_amdgcn_s_barrier();

  for (int T = 0; T < NT - 1; ++T) {
    const int c = T & 1, cN = c ^ 1;
    const int aN = cN * 32768, bN = 65536 + cN * 32768;

    // p0: Q(a0,b0) — reads A0,B0; stage B0(T+1)
    RD_A(af0, 0, c);
    RD_B(0, c);
    STG(pB0, bN, T + 1);
    GATE(4);
    __builtin_amdgcn_s_barrier();
    MM(af0, 0, 0);

    // p1: Q(a1,b0) — reads A1 (reuse bf); stage A0(T+1)
    RD_A(af1, 1, c);
    STG(pA0, aN, T + 1);
    GATE(4);
    __builtin_amdgcn_s_barrier();
    MM(af1, 1, 0);

    // p2: Q(a1,b1) — reads B1 (af1 held); stage A1(T+1)
    RD_B(1, c);
    STG(pA1, aN + 16384, T + 1);
    GATE(4);
    __builtin_amdgcn_s_barrier();
    MM(af1, 1, 1);

    // p3: Q(a0,b1) — NO reads (af0 held, bf held); stage B1(T+1)
    STG(pB1, bN + 16384, T + 1);
    GATE(4);
    __builtin_amdgcn_s_barrier();
    MM(af0, 0, 1);
  }

  // ---- tail tile (buf 1): no staging, tight gates ----
  {
    RD_A(af0, 0, 1);
    RD_B(0, 1);
    GATE(2);
    __builtin_amdgcn_s_barrier();
    MM(af0, 0, 0);
    RD_A(af1, 1, 1);
    GATE(0);
    __builtin_amdgcn_s_barrier();
    MM(af1, 1, 0);
    RD_B(1, 1);
    MM(af1, 1, 1);
    MM(af0, 0, 1);
  }
#undef STG
#undef RD_A
#undef RD_B
#undef MM
#undef GATE

  // ---- epilogue: C = sA[row]*(d[col]*wmax/255)*(acc + 128*rsA[row]) ----
  // non-temporal: C is write-once, keep L2 for A/B panels
  const float s2 = scal[0] * (1.0f / 255.0f);
  float dc[2][2];
#pragma unroll
  for (int b = 0; b < 2; ++b)
#pragma unroll
    for (int n = 0; n < 2; ++n)
      dc[b][n] = d[colBase + b * 128 + (wid >> 2) * 64 + n * 32 + l31] * s2;
#pragma unroll
  for (int a = 0; a < 2; ++a)
#pragma unroll
    for (int r = 0; r < 16; ++r) {
      const size_t row = rowBase + a * 128 + (wid & 3) * 32 + (r & 3) + 8 * (r >> 2) + 4 * hi32;
      const float fr = sA[row];
      const float rt = 128.0f * (float)rsA[row];
#pragma unroll
      for (int b = 0; b < 2; ++b)
#pragma unroll
        for (int n = 0; n < 2; ++n) {
          const size_t col = colBase + b * 128 + (wid >> 2) * 64 + n * 32 + l31;
          __builtin_nontemporal_store(fr * dc[b][n] * ((float)acc[a][b][n][r] + rt),
                                      &C[row * N_DIM + col]);
        }
    }
}

extern "C" void kernel_launch(void* const* d_in, const int* in_sizes, int n_in,
                              void* d_out, int out_size, void* d_ws, size_t ws_size,
                              hipStream_t stream) {
  const float* H = (const float*)d_in[0];   // [N, E]
  const float* R = (const float*)d_in[1];   // [E, N]
  const float* W = (const float*)d_in[2];   // [E]
  float* C = (float*)d_out;                 // [N, N]

  char* ws = (char*)d_ws;
  float* scal = (float*)ws;                              // [0]=wmax
  float* d    = (float*)(ws + 4096);                     // 32 KB
  float* sA   = (float*)(ws + 4096 + 32768);             // 32 KB
  int*   rsA  = (int*)  (ws + 4096 + 65536);             // 32 KB
  signed char* Ai = (signed char*)(ws + 131072);         // 32 MB
  signed char* Bi = Ai + (size_t)N_DIM * E_DIM;          // 32 MB

  k_prepA<<<N_DIM / 4, 256, 0, stream>>>(H, W, d, sA, rsA, scal, Ai);
  k_makeB<<<dim3(N_DIM / 128, E_DIM / 128), 256, 0, stream>>>(R, W, scal, Bi);
  k_gemm<<<(N_DIM / 256) * (N_DIM / 256), 512, 0, stream>>>(Ai, Bi, scal, sA, rsA, d, C);
}

// Round 18
// 334.205 us; speedup vs baseline: 1.0890x; 1.0890x over previous
//
#include <hip/hip_runtime.h>

#define N_DIM 8192
#define E_DIM 4096
#define BK    128
#define NT    (E_DIM / BK)   // 32 K-tiles

using int4v  = __attribute__((ext_vector_type(4))) int;
using i32x16 = __attribute__((ext_vector_type(16))) int;

__device__ __forceinline__ void async16(const void* g, void* l) {
  __builtin_amdgcn_global_load_lds(
      (const __attribute__((address_space(1))) unsigned int*)g,
      (__attribute__((address_space(3))) unsigned int*)l, 16, 0, 0);
}

// ---- kernel 1: fused degree + per-row quantize of A + rowsum + wmax ----
__global__ __launch_bounds__(256) void k_prepA(const float* __restrict__ H,
                                               const float* __restrict__ W,
                                               float* __restrict__ d,
                                               float* __restrict__ sA,
                                               int* __restrict__ rsA,
                                               float* __restrict__ wmax,
                                               signed char* __restrict__ A) {
  const int row  = blockIdx.x * 4 + (threadIdx.x >> 6);
  const int lane = threadIdx.x & 63;
  const float* hrow = H + (size_t)row * E_DIM;
  float4 h[16];
  float s = 0.f, m = 0.f, wm = 0.f;
#pragma unroll
  for (int i = 0; i < 16; ++i) {
    h[i] = *reinterpret_cast<const float4*>(hrow + lane * 4 + i * 256);
    float4 w = *reinterpret_cast<const float4*>(W + lane * 4 + i * 256);
    s += h[i].x * w.x + h[i].y * w.y + h[i].z * w.z + h[i].w * w.w;
    m = fmaxf(m, fmaxf(fmaxf(h[i].x, h[i].y), fmaxf(h[i].z, h[i].w)));
    wm = fmaxf(wm, fmaxf(fmaxf(w.x, w.y), fmaxf(w.z, w.w)));
  }
#pragma unroll
  for (int off = 1; off < 64; off <<= 1) {
    s += __shfl_xor(s, off);
    m = fmaxf(m, __shfl_xor(m, off));
    wm = fmaxf(wm, __shfl_xor(wm, off));
  }
  const float q = 127.0f / m;
  signed char* arow = A + (size_t)row * E_DIM;
  int rs = 0;
#pragma unroll
  for (int i = 0; i < 16; ++i) {
    const int b0 = __float2int_rn(h[i].x * q);
    const int b1 = __float2int_rn(h[i].y * q);
    const int b2 = __float2int_rn(h[i].z * q);
    const int b3 = __float2int_rn(h[i].w * q);
    rs += b0 + b1 + b2 + b3;
    const unsigned int pk = (unsigned)b0 | ((unsigned)b1 << 8) |
                            ((unsigned)b2 << 16) | ((unsigned)b3 << 24);
    *reinterpret_cast<unsigned int*>(arow + lane * 4 + i * 256) = pk;
  }
#pragma unroll
  for (int off = 1; off < 64; off <<= 1) rs += __shfl_xor(rs, off);
  if (lane == 0) {
    const float dv = rsqrtf(s);
    d[row]   = dv;
    sA[row]  = dv * m * (1.0f / 127.0f);
    rsA[row] = rs;
    if (blockIdx.x == 0 && threadIdx.x == 0) wmax[0] = wm;
  }
}

// ---- kernel 2: Bt_i8[j][e] = round(W_e*R[e][j]*255/wmax) - 128 (d_j cancels) ----
__global__ __launch_bounds__(256) void k_makeB(const float* __restrict__ R,
                                               const float* __restrict__ W,
                                               const float* __restrict__ scal,
                                               signed char* __restrict__ Bt) {
  __shared__ float ft[128][132];
  __shared__ float wlds[128];
  const int j0 = blockIdx.x * 128;
  const int e0 = blockIdx.y * 128;
  const int t = threadIdx.x;
  const int c4 = (t & 31) * 4;
#pragma unroll
  for (int r = (t >> 5); r < 128; r += 8) {
    float4 v = *reinterpret_cast<const float4*>(&R[(size_t)(e0 + r) * N_DIM + j0 + c4]);
    *reinterpret_cast<float4*>(&ft[r][c4]) = v;
  }
  if (t < 128) wlds[t] = W[e0 + t] * (255.0f / scal[0]);
  __syncthreads();
  const int r = t >> 1, p = t & 1;
  union { signed char c[64]; int4v i4[4]; } o;
#pragma unroll
  for (int e = 0; e < 64; ++e) {
    const int ee = p * 64 + e;
    o.c[e] = (signed char)(__float2int_rn(ft[ee][r] * wlds[ee]) - 128);
  }
  signed char* dstp = Bt + (size_t)(j0 + r) * E_DIM + e0 + p * 64;
#pragma unroll
  for (int s2 = 0; s2 < 4; ++s2)
    *reinterpret_cast<int4v*>(dstp + s2 * 16) = o.i4[s2];
}

// ---- kernel 3: 256x256 i8 MFMA GEMM — R16 exact (measured optimum) ----
// Per phase: [RD; STG one half; GATE(4); BAR; MM]; persistent af0/af1 (24
// ds_read_b128/wave/tile); XOR-swizzled row-major LDS (coalesced staging,
// residual 4-way read conflict is the cheaper side of the layout trade —
// R17 proved fragment-major costs more in staging scatter than it saves);
// 2-D XCD rectangles; no setprio; non-temporal C stores.
__global__ __launch_bounds__(512, 2) void k_gemm(const signed char* __restrict__ A,
                                                 const signed char* __restrict__ B,
                                                 const float* __restrict__ scal,
                                                 const float* __restrict__ sA,
                                                 const int* __restrict__ rsA,
                                                 const float* __restrict__ d,
                                                 float* __restrict__ C) {
  __shared__ alignas(16) signed char lds[131072];  // A: 2x32KB, B: 2x32KB

  // bid -> xcd (hw round-robin bid%8) -> 16x8 rect; round rr = 4x8 sub-rect
  const int bid  = blockIdx.x;          // 1024 blocks
  const int xcd  = bid & 7;
  const int loc  = bid >> 3;            // 0..127 within XCD
  const int rr   = loc >> 5;            // round 0..3
  const int pos  = loc & 31;
  const int tm   = (xcd >> 2) * 16 + rr * 4 + (pos >> 3);  // 0..31
  const int tn   = (xcd & 3) * 8 + (pos & 7);              // 0..31
  const size_t rowBase = (size_t)tm * 256;
  const size_t colBase = (size_t)tn * 256;

  const int t = threadIdx.x, wid = t >> 6, lane = t & 63;
  const int l31 = lane & 31, hi32 = lane >> 5;

  const signed char *pA0[2], *pA1[2], *pB0[2], *pB1[2];
#pragma unroll
  for (int j = 0; j < 2; ++j) {
    const int P  = j * 8192 + wid * 1024 + lane * 16;  // byte off in 16KB half
    const int rP = P >> 7;                             // row 0..127
    const int ce = (P ^ ((rP & 7) << 4)) & 127;        // pre-swizzled source col
    pA0[j] = A + (rowBase +       rP) * E_DIM + ce;
    pA1[j] = A + (rowBase + 128 + rP) * E_DIM + ce;
    pB0[j] = B + (colBase +       rP) * E_DIM + ce;
    pB1[j] = B + (colBase + 128 + rP) * E_DIM + ce;
  }
  const int dstw = wid * 1024;

#define STG(Pj, base_, kt)                                            \
  do {                                                                \
    async16(Pj[0] + (size_t)(kt) * BK, &lds[(base_) + dstw]);         \
    async16(Pj[1] + (size_t)(kt) * BK, &lds[(base_) + 8192 + dstw]);  \
  } while (0)

  const int rowAoff = ((wid & 3) * 32 + l31) * 128;
  const int rowBoff = ((wid >> 2) * 64 + l31) * 128;
  const int swz = (lane & 7) << 4;
  int colX[4];
#pragma unroll
  for (int k = 0; k < 4; ++k) colX[k] = (k * 32 + hi32 * 16) ^ swz;

  int4v af0[4], af1[4], bf[2][4];
  i32x16 acc[2][2][2] = {};  // [a-half][b-half][n]

#define RD_A(dst_, aH, cb)                                                        \
  do {                                                                            \
    _Pragma("unroll") for (int k = 0; k < 4; ++k)                                 \
      dst_[k] = *(const int4v*)&lds[(cb) * 32768 + (aH) * 16384 + rowAoff + colX[k]]; \
  } while (0)
#define RD_B(bH, cb)                                                              \
  do {                                                                            \
    _Pragma("unroll") for (int n = 0; n < 2; ++n)                                 \
      _Pragma("unroll") for (int k = 0; k < 4; ++k)                               \
        bf[n][k] = *(const int4v*)&lds[65536 + (cb) * 32768 + (bH) * 16384 +      \
                                       rowBoff + n * 4096 + colX[k]];             \
  } while (0)
#define MM(src_, a_, b_)                                                          \
  do {                                                                            \
    _Pragma("unroll") for (int n = 0; n < 2; ++n)                                 \
      _Pragma("unroll") for (int k = 0; k < 4; ++k)                               \
        acc[a_][b_][n] =                                                          \
            __builtin_amdgcn_mfma_i32_32x32x32_i8(src_[k], bf[n][k],              \
                                                  acc[a_][b_][n], 0, 0, 0);       \
  } while (0)
#define GATE(n_) asm volatile("s_waitcnt vmcnt(" #n_ ")" ::: "memory")

  // ---- prologue: stage tile 0 (A0,B0,A1,B1 -> buf0); gate(4) => A0,B0 landed ----
  STG(pA0, 0, 0);
  STG(pB0, 65536, 0);
  STG(pA1, 16384, 0);
  STG(pB1, 65536 + 16384, 0);
  GATE(4);
  __builtin_amdgcn_s_barrier();

  for (int T = 0; T < NT - 1; ++T) {
    const int c = T & 1, cN = c ^ 1;
    const int aN = cN * 32768, bN = 65536 + cN * 32768;

    // p0: Q(a0,b0) — reads A0,B0; stage B0(T+1)
    RD_A(af0, 0, c);
    RD_B(0, c);
    STG(pB0, bN, T + 1);
    GATE(4);
    __builtin_amdgcn_s_barrier();
    MM(af0, 0, 0);

    // p1: Q(a1,b0) — reads A1 (reuse bf); stage A0(T+1)
    RD_A(af1, 1, c);
    STG(pA0, aN, T + 1);
    GATE(4);
    __builtin_amdgcn_s_barrier();
    MM(af1, 1, 0);

    // p2: Q(a1,b1) — reads B1 (af1 held); stage A1(T+1)
    RD_B(1, c);
    STG(pA1, aN + 16384, T + 1);
    GATE(4);
    __builtin_amdgcn_s_barrier();
    MM(af1, 1, 1);

    // p3: Q(a0,b1) — NO reads (af0 held, bf held); stage B1(T+1)
    STG(pB1, bN + 16384, T + 1);
    GATE(4);
    __builtin_amdgcn_s_barrier();
    MM(af0, 0, 1);
  }

  // ---- tail tile (buf 1): no staging, tight gates ----
  {
    RD_A(af0, 0, 1);
    RD_B(0, 1);
    GATE(2);
    __builtin_amdgcn_s_barrier();
    MM(af0, 0, 0);
    RD_A(af1, 1, 1);
    GATE(0);
    __builtin_amdgcn_s_barrier();
    MM(af1, 1, 0);
    RD_B(1, 1);
    MM(af1, 1, 1);
    MM(af0, 0, 1);
  }
#undef STG
#undef RD_A
#undef RD_B
#undef MM
#undef GATE

  // ---- epilogue: C = sA[row]*(d[col]*wmax/255)*(acc + 128*rsA[row]) ----
  // non-temporal: C is write-once, keep L2 for A/B panels
  const float s2 = scal[0] * (1.0f / 255.0f);
  float dc[2][2];
#pragma unroll
  for (int b = 0; b < 2; ++b)
#pragma unroll
    for (int n = 0; n < 2; ++n)
      dc[b][n] = d[colBase + b * 128 + (wid >> 2) * 64 + n * 32 + l31] * s2;
#pragma unroll
  for (int a = 0; a < 2; ++a)
#pragma unroll
    for (int r = 0; r < 16; ++r) {
      const size_t row = rowBase + a * 128 + (wid & 3) * 32 + (r & 3) + 8 * (r >> 2) + 4 * hi32;
      const float fr = sA[row];
      const float rt = 128.0f * (float)rsA[row];
#pragma unroll
      for (int b = 0; b < 2; ++b)
#pragma unroll
        for (int n = 0; n < 2; ++n) {
          const size_t col = colBase + b * 128 + (wid >> 2) * 64 + n * 32 + l31;
          __builtin_nontemporal_store(fr * dc[b][n] * ((float)acc[a][b][n][r] + rt),
                                      &C[row * N_DIM + col]);
        }
    }
}

extern "C" void kernel_launch(void* const* d_in, const int* in_sizes, int n_in,
                              void* d_out, int out_size, void* d_ws, size_t ws_size,
                              hipStream_t stream) {
  const float* H = (const float*)d_in[0];   // [N, E]
  const float* R = (const float*)d_in[1];   // [E, N]
  const float* W = (const float*)d_in[2];   // [E]
  float* C = (float*)d_out;                 // [N, N]

  char* ws = (char*)d_ws;
  float* scal = (float*)ws;                              // [0]=wmax
  float* d    = (float*)(ws + 4096);                     // 32 KB
  float* sA   = (float*)(ws + 4096 + 32768);             // 32 KB
  int*   rsA  = (int*)  (ws + 4096 + 65536);             // 32 KB
  signed char* Ai = (signed char*)(ws + 131072);         // 32 MB
  signed char* Bi = Ai + (size_t)N_DIM * E_DIM;          // 32 MB

  k_prepA<<<N_DIM / 4, 256, 0, stream>>>(H, W, d, sA, rsA, scal, Ai);
  k_makeB<<<dim3(N_DIM / 128, E_DIM / 128), 256, 0, stream>>>(R, W, scal, Bi);
  k_gemm<<<(N_DIM / 256) * (N_DIM / 256), 512, 0, stream>>>(Ai, Bi, scal, sA, rsA, d, C);
}